// Round 10
// baseline (621.780 us; speedup 1.0000x reference)
//
#include <hip/hip_runtime.h>

#define SEQ 128
#define HID 32

typedef __attribute__((ext_vector_type(8))) short short8;   // 8 bf16 = 4 VGPR
typedef __attribute__((ext_vector_type(4))) float floatx4;  // MFMA acc

// ---------------- GCN prep ----------------
// RULE (round 9 lesson): buffers consumed by atomic-RMW must be initialized by
// hipMemsetAsync, NOT by plain kernel stores — plain-store -> atomic across a
// graph-node boundary intermittently lost updates on replay (non-coherent
// per-XCD L2). Plain-store -> plain-load (dinv, m2) is proven safe.

__global__ void count_kernel(const int* __restrict__ idx, int E, int* __restrict__ cnt) {
    int e = blockIdx.x * blockDim.x + threadIdx.x;
    if (e < E) atomicAdd(&cnt[idx[E + e]], 1);
}

// cnt -> dinv (in place); m2 = x * dinv (gather table for scatter).
__global__ void msg_kernel(float* __restrict__ dinv, const float2* __restrict__ x2,
                           float2* __restrict__ m2, int n) {
    int i = blockIdx.x * blockDim.x + threadIdx.x;
    if (i < n) {
        int c = __float_as_int(dinv[i]);
        float dv = rsqrtf((float)c + 1.0f);
        dinv[i] = dv;
        float2 xx = x2[i];
        m2[i] = make_float2(xx.x * dv, xx.y * dv);
    }
}

// fallback (small ws): no m2 table
__global__ void msg0_kernel(float* __restrict__ dinv, int n) {
    int i = blockIdx.x * blockDim.x + threadIdx.x;
    if (i < n) dinv[i] = rsqrtf((float)__float_as_int(dinv[i]) + 1.0f);
}

// one 8B gather per edge; atomics onto memset-zero agg2 (proven pattern)
__global__ void scatter_m2_kernel(const int* __restrict__ idx, int E,
                                  const float2* __restrict__ m2,
                                  float* __restrict__ agg2) {
    int e = blockIdx.x * blockDim.x + threadIdx.x;
    if (e < E) {
        int s = idx[e];
        int d = idx[E + e];
        float2 m = m2[s];
        atomicAdd(&agg2[2 * d + 0], m.x);
        atomicAdd(&agg2[2 * d + 1], m.y);
    }
}

__global__ void scatter_old_kernel(const int* __restrict__ idx, int E,
                                   const float2* __restrict__ x2,
                                   const float* __restrict__ dinv,
                                   float* __restrict__ agg2) {
    int e = blockIdx.x * blockDim.x + threadIdx.x;
    if (e < E) {
        int s = idx[e];
        int d = idx[E + e];
        float ns = dinv[s];
        float2 xs = x2[s];
        atomicAdd(&agg2[2 * d + 0], xs.x * ns);
        atomicAdd(&agg2[2 * d + 1], xs.y * ns);
    }
}

// ---------------- MFMA LSTM: single wave / 16 nodes, zero-shuffle ----------------
// Lane owns units 8q+j (j=0..7) of node l15. Tile T = gate*2+mtl, A-row
// permutation gate*32 + 8*(l15>>2) + 4*mtl + (l15&3) makes C/D slot (T,q,r) ==
// unit 8q+(4*mtl+r) == B-frag element k=8q+j  (HW-verified rounds 5-9).
// h never leaves registers; u staged in LDS once; NO barriers in the loop.
// Term-major MFMA: 8 independent tile-chains, dep distance 8 -> latency hidden.

__device__ __forceinline__ float sigm_f(float x) {
    return __builtin_amdgcn_rcpf(1.0f + __expf(-x));
}
__device__ __forceinline__ float tanh_f(float x) {
    return fmaf(__builtin_amdgcn_rcpf(1.0f + __expf(-2.0f * x)), 2.0f, -1.0f);
}
// truncation split: f = hi + lo (~2^-16 rel); 3-term MFMA ~= fp32 precision
__device__ __forceinline__ void fsplit(float f, short& hi, short& lo) {
    unsigned u = __float_as_uint(f);
    hi = (short)(u >> 16);
    float r = f - __uint_as_float(u & 0xFFFF0000u);
    lo = (short)(__float_as_uint(r) >> 16);
}
__device__ __forceinline__ float bf2f(short s) {
    return __uint_as_float(((unsigned)(unsigned short)s) << 16);
}

__global__ __launch_bounds__(64, 2) void lstm_mfma4_kernel(
    const float2* __restrict__ x2, const float* __restrict__ dinv,
    const float2* __restrict__ agg2, int N,
    const float* __restrict__ gcn_W, const float* __restrict__ gcn_b,
    const float* __restrict__ w_ih, const float* __restrict__ w_hh,
    const float* __restrict__ b_ih, const float* __restrict__ b_hh,
    const float* __restrict__ fc_W, const float* __restrict__ fc_b,
    float* __restrict__ out) {
    __shared__ float2 ubuf[16][SEQ + 1];   // 16.5 KB; col 128 = prefetch pad

    const int lane = threadIdx.x;
    const int l15 = lane & 15;
    const int q = lane >> 4;
    const int base = blockIdx.x * 16;

    // ---- Phase A: u[node][t] = dv*(agg + x*dv)  (self-loop folded; r7 math) ----
    {
        const float2* agb = agg2 + (size_t)base * SEQ;
        const float2* xb  = x2   + (size_t)base * SEQ;
        const float*  db  = dinv + (size_t)base * SEQ;
        const int lim = min(16 * SEQ, (N - base) * SEQ);
        for (int i = lane; i < 16 * SEQ; i += 64) {
            float2 v = make_float2(0.f, 0.f);
            if (i < lim) {
                float dv = db[i];
                float2 a = agb[i];
                float2 xx = xb[i];
                v = make_float2(dv * fmaf(xx.x, dv, a.x), dv * fmaf(xx.y, dv, a.y));
            }
            ubuf[i >> 7][i & 127] = v;
        }
    }

    // ---- constant A-frags (8 tiles), hi/lo bf16 split ----
    short8 AiH[8], AiL[8], AhH[8], AhL[8];
    floatx4 biasC[8];
    #pragma unroll
    for (int T = 0; T < 8; ++T) {
        const int gate = T >> 1, mtl = T & 1;
        const int arow = gate * 32 + 8 * (l15 >> 2) + 4 * mtl + (l15 & 3);
        const float* wi = w_ih + arow * HID + 8 * q;
        const float* wh = w_hh + arow * HID + 8 * q;
        #pragma unroll
        for (int j = 0; j < 8; ++j) {
            short h16, l16;
            fsplit(wi[j], h16, l16); AiH[T][j] = h16; AiL[T][j] = l16;
            fsplit(wh[j], h16, l16); AhH[T][j] = h16; AhL[T][j] = l16;
        }
        #pragma unroll
        for (int r = 0; r < 4; ++r) {
            const int brow = gate * 32 + 8 * q + 4 * mtl + r;
            biasC[T][r] = b_ih[brow] + b_hh[brow];
        }
    }

    // ---- GCN consts for units 8q+j ----
    float wg0[8], wg1[8], gbc[8];
    #pragma unroll
    for (int j = 0; j < 8; ++j) {
        const int u = 8 * q + j;
        wg0[j] = gcn_W[u];
        wg1[j] = gcn_W[HID + u];
        gbc[j] = gcn_b[u];
    }

    short8 hh, hl;
    float c[8];
    #pragma unroll
    for (int j = 0; j < 8; ++j) { hh[j] = 0; hl[j] = 0; c[j] = 0.f; }

    __syncthreads();   // single wave: cheap (LDS drain only)

    float2 uu = ubuf[l15][0];
    #pragma unroll 1
    for (int t = 0; t < SEQ; ++t) {
        float2 un = ubuf[l15][t + 1];   // prefetch (t=127 reads pad, unused)

        // xg for units 8q+j, hi/lo split
        short8 xh, xl;
        #pragma unroll
        for (int j = 0; j < 8; ++j) {
            float g = fmaxf(fmaf(uu.x, wg0[j], fmaf(uu.y, wg1[j], gbc[j])), 0.f);
            short h16, l16;
            fsplit(g, h16, l16);
            xh[j] = h16; xl[j] = l16;
        }

        // term-major MFMA: 8 independent chains, dep distance 8
        floatx4 acc[8];
        #pragma unroll
        for (int T = 0; T < 8; ++T) acc[T] = biasC[T];
        #pragma unroll
        for (int T = 0; T < 8; ++T) acc[T] = __builtin_amdgcn_mfma_f32_16x16x32_bf16(AiH[T], xh, acc[T], 0, 0, 0);
        #pragma unroll
        for (int T = 0; T < 8; ++T) acc[T] = __builtin_amdgcn_mfma_f32_16x16x32_bf16(AiL[T], xh, acc[T], 0, 0, 0);
        #pragma unroll
        for (int T = 0; T < 8; ++T) acc[T] = __builtin_amdgcn_mfma_f32_16x16x32_bf16(AiH[T], xl, acc[T], 0, 0, 0);
        #pragma unroll
        for (int T = 0; T < 8; ++T) acc[T] = __builtin_amdgcn_mfma_f32_16x16x32_bf16(AhH[T], hh, acc[T], 0, 0, 0);
        #pragma unroll
        for (int T = 0; T < 8; ++T) acc[T] = __builtin_amdgcn_mfma_f32_16x16x32_bf16(AhL[T], hh, acc[T], 0, 0, 0);
        #pragma unroll
        for (int T = 0; T < 8; ++T) acc[T] = __builtin_amdgcn_mfma_f32_16x16x32_bf16(AhH[T], hl, acc[T], 0, 0, 0);

        // activations + cell update; slot j: gate g at acc[2g + (j>>2)][j&3]
        #pragma unroll
        for (int j = 0; j < 8; ++j) {
            const int tt = j >> 2, r = j & 3;
            const float ig = sigm_f(acc[0 + tt][r]);
            const float fg = sigm_f(acc[2 + tt][r]);
            const float gg = tanh_f(acc[4 + tt][r]);
            const float og = sigm_f(acc[6 + tt][r]);
            c[j] = fmaf(fg, c[j], ig * gg);
            const float hv = og * tanh_f(c[j]);
            short h16, l16;
            fsplit(hv, h16, l16);
            hh[j] = h16; hl[j] = l16;
        }

        uu = un;
    }

    // ---- FC epilogue: h reconstructed from hi+lo ----
    float partial = 0.f;
    #pragma unroll
    for (int j = 0; j < 8; ++j) {
        float hv = bf2f(hh[j]) + bf2f(hl[j]);
        partial = fmaf(hv, fc_W[8 * q + j], partial);
    }
    partial += __shfl_xor(partial, 16);
    partial += __shfl_xor(partial, 32);
    const int node = base + l15;
    if (q == 0 && node < N) out[node] = partial + fc_b[0];
}

extern "C" void kernel_launch(void* const* d_in, const int* in_sizes, int n_in,
                              void* d_out, int out_size, void* d_ws, size_t ws_size,
                              hipStream_t stream) {
    const float* x     = (const float*)d_in[0];
    const int*   idx   = (const int*)d_in[1];
    const float* gcn_W = (const float*)d_in[2];
    const float* gcn_b = (const float*)d_in[3];
    const float* w_ih  = (const float*)d_in[4];
    const float* w_hh  = (const float*)d_in[5];
    const float* b_ih  = (const float*)d_in[6];
    const float* b_hh  = (const float*)d_in[7];
    const float* fc_W  = (const float*)d_in[8];
    const float* fc_b  = (const float*)d_in[9];

    const int num_nodes = in_sizes[0] / (SEQ * 2);
    const int ntot = num_nodes * SEQ;
    const int E = in_sizes[1] / 2;

    // ws layout: [cnt/dinv: ntot f32][agg2: ntot float2][m2: ntot float2]
    float*  dinv = (float*)d_ws;
    float*  agg2 = dinv + ntot;
    float2* m2   = (float2*)(dinv + 3 * (size_t)ntot);
    const bool big_ws = ws_size >= (size_t)ntot * 5 * sizeof(float);

    // memset covers dinv + agg2 (atomic destinations) — proven-safe init
    hipMemsetAsync(d_ws, 0, (size_t)ntot * 3 * sizeof(float), stream);
    count_kernel<<<(E + 255) / 256, 256, 0, stream>>>(idx, E, (int*)dinv);

    if (big_ws) {
        msg_kernel<<<(ntot + 255) / 256, 256, 0, stream>>>(
            dinv, (const float2*)x, m2, ntot);
        scatter_m2_kernel<<<(E + 255) / 256, 256, 0, stream>>>(
            idx, E, (const float2*)m2, agg2);
    } else {
        msg0_kernel<<<(ntot + 255) / 256, 256, 0, stream>>>(dinv, ntot);
        scatter_old_kernel<<<(E + 255) / 256, 256, 0, stream>>>(
            idx, E, (const float2*)x, dinv, agg2);
    }

    lstm_mfma4_kernel<<<(num_nodes + 15) / 16, 64, 0, stream>>>(
        (const float2*)x, dinv, (const float2*)agg2, num_nodes,
        gcn_W, gcn_b, w_ih, w_hh, b_ih, b_hh, fc_W, fc_b,
        (float*)d_out);
}